// Round 2
// baseline (233.728 us; speedup 1.0000x reference)
//
#include <hip/hip_runtime.h>

// out[w,h] = -( (Σ_k fl(1e-14*W[k])·x[3w+k/3, 3h+k%3]) / fl(c2) ) * 1500
// folded to: out = Σ_k (G·W[k])·v_k,  G = -(1e-14*1500)/fl(0.924458e-14*1500) ≈ -1.08157
// (absmax slack vs jax reference is 0.0625; reassociation noise ~1e-6 is free)
//
// DIAGNOSTIC this round: kernel launched TWICE into d_out (idempotent).
// dur_us(R2) - dur_us(R1) ≈ true kernel time (L3-warm), since rocprof top-5
// is saturated by the harness's 88us d_ws poison fills and can't show us.

#define IN_W 6144
#define OUT_H 2048
#define OUT_W 2048
#define QW 512      // OUT_W/4, one thread -> 4 adjacent outputs

__global__ __launch_bounds__(256) void conv3x3_sc_kernel(
    const float* __restrict__ x,
    const float* __restrict__ w,
    float* __restrict__ out)
{
    const int t  = blockIdx.x * blockDim.x + threadIdx.x;  // grid is exact: 1M threads
    const int ow = t >> 9;        // output row
    const int hq = t & (QW - 1);  // quad-column

    // single folded gain, computed like Python: double math, one fp32 round for c2
    const float G = (float)(-(1e-14 * 1500.0) / (double)(float)(0.924458 * 1e-14 * 1500.0));
    float g[9];
#pragma unroll
    for (int i = 0; i < 9; ++i) g[i] = __fmul_rn(G, w[i]);

    const float* r0 = x + (size_t)(3 * ow) * IN_W + 12 * hq;  // 48B-aligned
    const float* r1 = r0 + IN_W;
    const float* r2 = r1 + IN_W;

    const float4 a0 = *(const float4*)(r0);
    const float4 a1 = *(const float4*)(r0 + 4);
    const float4 a2 = *(const float4*)(r0 + 8);
    const float4 b0 = *(const float4*)(r1);
    const float4 b1 = *(const float4*)(r1 + 4);
    const float4 b2 = *(const float4*)(r1 + 8);
    const float4 c0 = *(const float4*)(r2);
    const float4 c1 = *(const float4*)(r2 + 4);
    const float4 c2 = *(const float4*)(r2 + 8);

    const float ra[12] = {a0.x,a0.y,a0.z,a0.w, a1.x,a1.y,a1.z,a1.w, a2.x,a2.y,a2.z,a2.w};
    const float rb[12] = {b0.x,b0.y,b0.z,b0.w, b1.x,b1.y,b1.z,b1.w, b2.x,b2.y,b2.z,b2.w};
    const float rc[12] = {c0.x,c0.y,c0.z,c0.w, c1.x,c1.y,c1.z,c1.w, c2.x,c2.y,c2.z,c2.w};

    float o[4];
#pragma unroll
    for (int k = 0; k < 4; ++k) {
        const int cb = 3 * k;
        float acc =      __fmul_rn(g[0], ra[cb + 0]);
        acc = __fmaf_rn(g[1], ra[cb + 1], acc);
        acc = __fmaf_rn(g[2], ra[cb + 2], acc);
        acc = __fmaf_rn(g[3], rb[cb + 0], acc);
        acc = __fmaf_rn(g[4], rb[cb + 1], acc);
        acc = __fmaf_rn(g[5], rb[cb + 2], acc);
        acc = __fmaf_rn(g[6], rc[cb + 0], acc);
        acc = __fmaf_rn(g[7], rc[cb + 1], acc);
        acc = __fmaf_rn(g[8], rc[cb + 2], acc);
        o[k] = acc;
    }

    *(float4*)(out + (size_t)ow * OUT_W + 4 * hq) =
        make_float4(o[0], o[1], o[2], o[3]);
}

extern "C" void kernel_launch(void* const* d_in, const int* in_sizes, int n_in,
                              void* d_out, int out_size, void* d_ws, size_t ws_size,
                              hipStream_t stream) {
    (void)in_sizes; (void)n_in; (void)out_size; (void)d_ws; (void)ws_size;
    const float* x = (const float*)d_in[0];
    const float* w = (const float*)d_in[1];
    float* out = (float*)d_out;

    const int total = OUT_H * QW;                  // 1,048,576
    const int block = 256;
    const int grid  = total / block;               // 4096, exact

    // launch 1: the real computation (cold-ish input, post-restore)
    conv3x3_sc_kernel<<<grid, block, 0, stream>>>(x, w, out);
    // launch 2: identical, idempotent — diagnostic to expose kernel duration
    // in dur_us delta vs round 1 (rocprof top-5 is saturated by harness fills)
    conv3x3_sc_kernel<<<grid, block, 0, stream>>>(x, w, out);
}

// Round 4
// 211.156 us; speedup vs baseline: 1.1069x; 1.1069x over previous
//
#include <hip/hip_runtime.h>

// out[w,h] = -( (Σ_k fl(1e-14*W[k])·x[3w+k/3, 3h+k%3]) / fl(c2) ) * 1500
// folded to: out = Σ_k (G·W[k])·v_k,  G = -(1e-14*1500)/fl(0.924458e-14*1500) ≈ -1.08157
// (validated: absmax 0.0625 vs jax reference — same as the bit-exact div form)
//
// Measured (R1/R2 double-launch diagnostic): kernel ≈ 22.4 us L3-warm,
// ≈ 27 us HBM floor cold -> at the memory roofline. dur_us is dominated by
// ~185 us of fixed harness reset traffic (576 MiB d_ws poison fill etc.).

#define IN_W 6144
#define OUT_H 2048
#define OUT_W 2048
#define QW 512      // OUT_W/4, one thread -> 4 adjacent outputs

__global__ __launch_bounds__(256) void conv3x3_sc_kernel(
    const float* __restrict__ x,
    const float* __restrict__ w,
    float* __restrict__ out)
{
    const int t  = blockIdx.x * blockDim.x + threadIdx.x;  // grid exact: 1M threads
    const int ow = t >> 9;        // output row
    const int hq = t & (QW - 1);  // quad-column

    // single folded gain, computed like Python: double math, one fp32 round for c2
    const float G = (float)(-(1e-14 * 1500.0) / (double)(float)(0.924458 * 1e-14 * 1500.0));
    float g[9];
#pragma unroll
    for (int i = 0; i < 9; ++i) g[i] = __fmul_rn(G, w[i]);

    const float* r0 = x + (size_t)(3 * ow) * IN_W + 12 * hq;  // 48B-aligned
    const float* r1 = r0 + IN_W;
    const float* r2 = r1 + IN_W;

    const float4 a0 = *(const float4*)(r0);
    const float4 a1 = *(const float4*)(r0 + 4);
    const float4 a2 = *(const float4*)(r0 + 8);
    const float4 b0 = *(const float4*)(r1);
    const float4 b1 = *(const float4*)(r1 + 4);
    const float4 b2 = *(const float4*)(r1 + 8);
    const float4 c0 = *(const float4*)(r2);
    const float4 c1 = *(const float4*)(r2 + 4);
    const float4 c2 = *(const float4*)(r2 + 8);

    const float ra[12] = {a0.x,a0.y,a0.z,a0.w, a1.x,a1.y,a1.z,a1.w, a2.x,a2.y,a2.z,a2.w};
    const float rb[12] = {b0.x,b0.y,b0.z,b0.w, b1.x,b1.y,b1.z,b1.w, b2.x,b2.y,b2.z,b2.w};
    const float rc[12] = {c0.x,c0.y,c0.z,c0.w, c1.x,c1.y,c1.z,c1.w, c2.x,c2.y,c2.z,c2.w};

    float o[4];
#pragma unroll
    for (int k = 0; k < 4; ++k) {
        const int cb = 3 * k;
        float acc =      __fmul_rn(g[0], ra[cb + 0]);
        acc = __fmaf_rn(g[1], ra[cb + 1], acc);
        acc = __fmaf_rn(g[2], ra[cb + 2], acc);
        acc = __fmaf_rn(g[3], rb[cb + 0], acc);
        acc = __fmaf_rn(g[4], rb[cb + 1], acc);
        acc = __fmaf_rn(g[5], rb[cb + 2], acc);
        acc = __fmaf_rn(g[6], rc[cb + 0], acc);
        acc = __fmaf_rn(g[7], rc[cb + 1], acc);
        acc = __fmaf_rn(g[8], rc[cb + 2], acc);
        o[k] = acc;
    }

    *(float4*)(out + (size_t)ow * OUT_W + 4 * hq) =
        make_float4(o[0], o[1], o[2], o[3]);
}

extern "C" void kernel_launch(void* const* d_in, const int* in_sizes, int n_in,
                              void* d_out, int out_size, void* d_ws, size_t ws_size,
                              hipStream_t stream) {
    (void)in_sizes; (void)n_in; (void)out_size; (void)d_ws; (void)ws_size;
    const float* x = (const float*)d_in[0];
    const float* w = (const float*)d_in[1];
    float* out = (float*)d_out;

    const int total = OUT_H * QW;                  // 1,048,576
    const int block = 256;
    const int grid  = total / block;               // 4096, exact

    conv3x3_sc_kernel<<<grid, block, 0, stream>>>(x, w, out);
}